// Round 8
// baseline (125.463 us; speedup 1.0000x reference)
//
#include <hip/hip_runtime.h>

// Head: B=4, T=4096, C=1024, H=64. out = softmax(causal((x@Wq+bq)@(x@Wk+bk)^T * C^-0.5)) @ (x@Wv+bv)
#define B_ 4
#define T_ 4096
#define C_ 1024
#define H_ 64
// C^-0.5 * log2(e): folds softmax scale into Q, moves softmax into exp2 domain.
#define QSCALE 0.045084220027780106f

typedef float  f32x4  __attribute__((ext_vector_type(4)));
typedef __bf16 bf16x8 __attribute__((ext_vector_type(8)));
typedef __bf16 bf16x4 __attribute__((ext_vector_type(4)));

#define MFMA16(a, b, c) __builtin_amdgcn_mfma_f32_16x16x32_bf16((a), (b), (c), 0, 0, 0)

// async global->LDS, 16B per lane; LDS dest is wave-uniform base + lane*16.
__device__ __forceinline__ void gl16(const void* g, void* l) {
    __builtin_amdgcn_global_load_lds(
        (const __attribute__((address_space(1))) void*)g,
        (__attribute__((address_space(3))) void*)l, 16, 0, 0);
}

// ---------------------------------------------------------------------------
// prep: Wt[mat][n][k] = W_mat[k][n] as bf16 (LDS tile transpose). 192 blocks.
// ---------------------------------------------------------------------------
__global__ __launch_bounds__(256) void prep_wt(const float* __restrict__ Wk,
                                               const float* __restrict__ Wq,
                                               const float* __restrict__ Wv,
                                               __bf16* __restrict__ Wt) {
    __shared__ float tile[16][65];
    int tid = threadIdx.x;
    int mat = blockIdx.x >> 6;
    int k0  = (blockIdx.x & 63) * 16;
    const float* W = (mat == 0) ? Wk : ((mat == 1) ? Wq : Wv);
#pragma unroll
    for (int i = 0; i < 4; ++i) {
        int e = i * 256 + tid;
        int ki = e >> 6, n = e & 63;
        tile[ki][n] = W[(size_t)(k0 + ki) * 64 + n];
    }
    __syncthreads();
#pragma unroll
    for (int i = 0; i < 4; ++i) {
        int e = i * 256 + tid;
        int n = e >> 4, kj = e & 15;
        Wt[(size_t)mat * 65536 + (size_t)n * 1024 + k0 + kj] = (__bf16)tile[kj][n];
    }
}

// ---------------------------------------------------------------------------
// proj: m97-style LDS-staged GEMM (R5 version, measured ~18.5us).
// ---------------------------------------------------------------------------
#define STAGE(xd, wd, kk) do {                                              \
    const char* xs_ = xsrc + (size_t)(kk) * 4;                              \
    gl16(xs_,          (xd) + wq * 1024);                                   \
    gl16(xs_ + 65536,  (xd) + 4096 + wq * 1024);                            \
    const char* ws_ = wsrc + (size_t)(kk) * 2;                              \
    gl16(ws_,           (wd) + wq * 1024);                                  \
    gl16(ws_ + 65536,   (wd) + 4096  + wq * 1024);                          \
    gl16(ws_ + 131072,  (wd) + 8192  + wq * 1024);                          \
    gl16(ws_ + 196608,  (wd) + 12288 + wq * 1024);                          \
    gl16(ws_ + 262144,  (wd) + 16384 + wq * 1024);                          \
    gl16(ws_ + 327680,  (wd) + 20480 + wq * 1024);                          \
} while (0)

__global__ __launch_bounds__(256) void proj_qkv(const float* __restrict__ x,
                                                const __bf16* __restrict__ Wt,
                                                const float* __restrict__ bk,
                                                const float* __restrict__ bq,
                                                const float* __restrict__ bv,
                                                __bf16* __restrict__ Kg,
                                                __bf16* __restrict__ Qg,
                                                __bf16* __restrict__ Vt) {
    __shared__ char smem[65536];

    int tid  = threadIdx.x;
    int wq   = tid >> 6;
    int lane = tid & 63;
    int lo = lane & 15, g = lane >> 4;
    int swz = lo & 7;
    int w2 = wq >> 1, wc = wq & 1;
    int r0 = w2 * 16, n0 = wc * 96;
    int row0 = blockIdx.x * 32;

    const char* xsrc = (const char*)(x + (size_t)(row0 + (tid >> 4)) * C_
                                       + (size_t)(((tid & 15) ^ ((tid >> 4) & 7)) * 4));
    const char* wsrc = (const char*)Wt + (size_t)(tid >> 3) * 2048
                                       + (size_t)(((tid & 7) ^ ((tid >> 3) & 7)) * 16);

    char* xcur = smem;          char* xnxt = smem + 8192;
    char* wcur = smem + 16384;  char* wnxt = smem + 40960;

    f32x4 acc[6];
#pragma unroll
    for (int nt = 0; nt < 6; ++nt) acc[nt] = (f32x4){0.f, 0.f, 0.f, 0.f};

    STAGE(xcur, wcur, 0);
    __syncthreads();

#pragma unroll 1
    for (int step = 0; step < 16; ++step) {
        if (step < 15) STAGE(xnxt, wnxt, (step + 1) * 64);

        bf16x8 af[2];
        const char* ap = xcur + (r0 + lo) * 256;
#pragma unroll
        for (int kc = 0; kc < 2; ++kc) {
            int ch0 = kc * 8 + g * 2;
            f32x4 a0 = *(const f32x4*)(ap + ((ch0)     ^ swz) * 16);
            f32x4 a1 = *(const f32x4*)(ap + ((ch0 + 1) ^ swz) * 16);
            bf16x8 t;
            t[0] = (__bf16)a0[0]; t[1] = (__bf16)a0[1];
            t[2] = (__bf16)a0[2]; t[3] = (__bf16)a0[3];
            t[4] = (__bf16)a1[0]; t[5] = (__bf16)a1[1];
            t[6] = (__bf16)a1[2]; t[7] = (__bf16)a1[3];
            af[kc] = t;
        }
#pragma unroll
        for (int nt = 0; nt < 6; ++nt) {
            const char* bp_ = wcur + (n0 + nt * 16 + lo) * 128;
#pragma unroll
            for (int kc = 0; kc < 2; ++kc) {
                bf16x8 bf_ = *(const bf16x8*)(bp_ + ((kc * 4 + g) ^ swz) * 16);
                acc[nt] = MFMA16(af[kc], bf_, acc[nt]);
            }
        }
        __syncthreads();
        char* t1 = xcur; xcur = xnxt; xnxt = t1;
        char* t2 = wcur; wcur = wnxt; wnxt = t2;
    }

    int b_   = row0 >> 12;
    int tloc = row0 & (T_ - 1);
#pragma unroll
    for (int nt = 0; nt < 6; ++nt) {
        int col = n0 + nt * 16 + lo;
        int mat = col >> 6, h = col & 63;
        const float* bp = (mat == 0) ? bk : ((mat == 1) ? bq : bv);
        float bb = bp[h];
        if (mat == 2) {                            // V -> transposed [B][64][T]
            bf16x4 pv;
#pragma unroll
            for (int r = 0; r < 4; ++r) pv[r] = (__bf16)(acc[nt][r] + bb);
            *(bf16x4*)(Vt + (size_t)(b_ * 64 + h) * T_ + tloc + r0 + 4 * g) = pv;
        } else if (mat == 1) {
#pragma unroll
            for (int r = 0; r < 4; ++r)
                Qg[(size_t)(row0 + r0 + 4 * g + r) * H_ + h] = (__bf16)((acc[nt][r] + bb) * QSCALE);
        } else {
#pragma unroll
            for (int r = 0; r < 4; ++r)
                Kg[(size_t)(row0 + r0 + 4 * g + r) * H_ + h] = (__bf16)(acc[nt][r] + bb);
        }
    }
}

// ---------------------------------------------------------------------------
// attn helpers
// ---------------------------------------------------------------------------
struct KFrag { bf16x8 a0[4]; bf16x8 a1[4]; };   // one 64-row K tile, A-frags

__device__ __forceinline__ void loadK(const __bf16* __restrict__ kgB, int k0,
                                      int lo, int g, KFrag& kf) {
#pragma unroll
    for (int kt = 0; kt < 4; ++kt) {
        const __bf16* kp = kgB + (size_t)(k0 + kt * 16 + lo) * H_ + g * 8;
        kf.a0[kt] = *(const bf16x8*)(kp);
        kf.a1[kt] = *(const bf16x8*)(kp + 32);
    }
}

// one flash iteration; K already in registers (kf).
__device__ __forceinline__ void attn_iter(const KFrag& kf,
                                          const __bf16* __restrict__ vtB,
                                          int k0, int q0, bool domask,
                                          bf16x8 qb0, bf16x8 qb1,
                                          f32x4 (&acc)[4], float& m, float& l,
                                          char* pl, int lo, int g) {
    f32x4 st[4];
#pragma unroll
    for (int kt = 0; kt < 4; ++kt) {
        f32x4 z = (f32x4){0.f, 0.f, 0.f, 0.f};
        __builtin_amdgcn_s_setprio(1);
        z = MFMA16(kf.a0[kt], qb0, z);             // col=q=lo, row=k=4g+r
        z = MFMA16(kf.a1[kt], qb1, z);
        __builtin_amdgcn_s_setprio(0);
        st[kt] = z;
    }
    if (domask) {
#pragma unroll
        for (int kt = 0; kt < 4; ++kt)
#pragma unroll
            for (int r = 0; r < 4; ++r) {
                int kabs = k0 + kt * 16 + 4 * g + r;
                if (kabs > q0 + lo) st[kt][r] = -1e30f;
            }
    }
    float mloc = -1e30f;
#pragma unroll
    for (int kt = 0; kt < 4; ++kt)
#pragma unroll
        for (int r = 0; r < 4; ++r) mloc = fmaxf(mloc, st[kt][r]);
    mloc = fmaxf(mloc, __shfl_xor(mloc, 16));
    mloc = fmaxf(mloc, __shfl_xor(mloc, 32));
    float mnew  = fmaxf(m, mloc);
    float alpha = exp2f(m - mnew);
    float ls = 0.f;
#pragma unroll
    for (int kt = 0; kt < 4; ++kt)
#pragma unroll
        for (int r = 0; r < 4; ++r) {
            float pe = exp2f(st[kt][r] - mnew);
            st[kt][r] = pe;
            ls += pe;
        }
    ls += __shfl_xor(ls, 16);
    ls += __shfl_xor(ls, 32);
    l = l * alpha + ls;
    m = mnew;
#pragma unroll
    for (int r = 0; r < 4; ++r) {
        float ar = __shfl(alpha, 4 * g + r);
#pragma unroll
        for (int ht = 0; ht < 4; ++ht) acc[ht][r] *= ar;
    }
#pragma unroll
    for (int kt = 0; kt < 4; ++kt) {
        bf16x4 pk;
#pragma unroll
        for (int r = 0; r < 4; ++r) pk[r] = (__bf16)st[kt][r];
        int waddr = (lo * 128 + kt * 32 + g * 8) ^ ((lo & 7) << 4);
        *(bf16x4*)(pl + waddr) = pk;
    }
#pragma unroll
    for (int c = 0; c < 2; ++c) {
        int raddr = (lo * 128 + c * 64 + g * 16) ^ ((lo & 7) << 4);
        bf16x8 pa = *(const bf16x8*)(pl + raddr);
        __builtin_amdgcn_s_setprio(1);
#pragma unroll
        for (int ht = 0; ht < 4; ++ht) {
            bf16x8 vb = *(const bf16x8*)(vtB + (size_t)(ht * 16 + lo) * T_ + k0 + c * 32 + g * 8);
            acc[ht] = MFMA16(pa, vb, acc[ht]);
        }
        __builtin_amdgcn_s_setprio(0);
    }
}

// ---------------------------------------------------------------------------
// attn: 512 blocks x 8 waves. Block = complementary q-tile pair (i, 255-i):
// niter(i)+niter(255-i) == 65 for all i -> uniform work. K tiles prefetched
// one iteration ahead into registers (double-buffered KFrag, 2-unrolled
// rotation) so K-load latency hides under the previous iteration's compute.
// __launch_bounds__(512,4): cap VGPR at 128 (the grid-limited 4-waves/SIMD
// class), so the prefetch buffers are occupancy-free.
// ---------------------------------------------------------------------------
#define DO_ITER(IDX, KF)                                                       \
    do {                                                                       \
        if ((IDX) < nA) {                                                      \
            attn_iter(KF, vtB, (IDX) << 6, q0A, (IDX) == nA - 1,               \
                      qA0, qA1, accA, mA, lA, pl, lo, g);                      \
        } else {                                                               \
            int kb_ = (IDX) - nA;                                              \
            attn_iter(KF, vtB, kb_ << 6, q0B, kb_ == nB - 1,                   \
                      qB0, qB1, accB, mB, lB, pl, lo, g);                      \
        }                                                                      \
    } while (0)

__global__ __launch_bounds__(512, 4) void attn_fwd(const __bf16* __restrict__ Qg,
                                                   const __bf16* __restrict__ Kg,
                                                   const __bf16* __restrict__ Vt,
                                                   float* __restrict__ out) {
    __shared__ alignas(16) char smem[32768 + 1024];

    int tid  = threadIdx.x;
    int w    = tid >> 6;
    int lane = tid & 63;
    int lo = lane & 15, g = lane >> 4;

    int bid = blockIdx.x;
    int b   = bid & 3;
    int i   = bid >> 2;                            // 0..127
    int q0A = i * 16;
    int q0B = (255 - i) * 16;
    int nA  = (q0A >> 6) + 1;
    int nB  = (q0B >> 6) + 1;
    int ntot = nA + nB;                            // == 65 for all i

    const __bf16* kgB = Kg + (size_t)b * T_ * H_;
    const __bf16* vtB = Vt + (size_t)b * 64 * T_;

    char* pl = smem + w * 2048;                    // wave-private P buffer

    const __bf16* qpA = Qg + (size_t)(b * T_ + q0A + lo) * H_ + g * 8;
    bf16x8 qA0 = *(const bf16x8*)(qpA);
    bf16x8 qA1 = *(const bf16x8*)(qpA + 32);
    const __bf16* qpB = Qg + (size_t)(b * T_ + q0B + lo) * H_ + g * 8;
    bf16x8 qB0 = *(const bf16x8*)(qpB);
    bf16x8 qB1 = *(const bf16x8*)(qpB + 32);

    f32x4 accA[4], accB[4];
#pragma unroll
    for (int ht = 0; ht < 4; ++ht) {
        accA[ht] = (f32x4){0.f, 0.f, 0.f, 0.f};
        accB[ht] = (f32x4){0.f, 0.f, 0.f, 0.f};
    }
    float mA = -1e30f, lA = 0.f, mB = -1e30f, lB = 0.f;

    // k0 of iteration slot idx (whichever tile it belongs to)
    auto k0_of = [&](int idx) { return (idx < nA ? idx : idx - nA) << 6; };

    KFrag kfA, kfB;
    int idx = w;
    if (idx < ntot) loadK(kgB, k0_of(idx), lo, g, kfA);
#pragma unroll 1
    while (idx < ntot) {
        int nx = idx + 8;
        if (nx < ntot) loadK(kgB, k0_of(nx), lo, g, kfB);   // prefetch ahead
        DO_ITER(idx, kfA);
        idx = nx;
        if (idx >= ntot) break;
        nx = idx + 8;
        if (nx < ntot) loadK(kgB, k0_of(nx), lo, g, kfA);   // prefetch ahead
        DO_ITER(idx, kfB);
        idx = nx;
    }

    float* ml = (float*)(smem + 32768);            // [8][16][2]

    // ---- pass A: merge tile-A partials ----
    __syncthreads();                               // all waves done with P bufs
    {
        float* ab = (float*)(smem + w * 4096);     // [16][64]
#pragma unroll
        for (int ht = 0; ht < 4; ++ht)
#pragma unroll
            for (int r = 0; r < 4; ++r)
                ab[(4 * g + r) * 64 + ht * 16 + lo] = accA[ht][r];
        if (g == 0) {
            ml[(w * 16 + lo) * 2 + 0] = mA;
            ml[(w * 16 + lo) * 2 + 1] = lA;
        }
    }
    __syncthreads();
    {
        const float* fl = (const float*)smem;
#pragma unroll
        for (int jj = 0; jj < 2; ++jj) {
            int e = jj * 512 + tid;
            int q = e >> 6, h = e & 63;
            float M = -1e30f;
#pragma unroll
            for (int ww = 0; ww < 8; ++ww) M = fmaxf(M, ml[(ww * 16 + q) * 2]);
            float L = 0.f, O = 0.f;
#pragma unroll
            for (int ww = 0; ww < 8; ++ww) {
                float sc = exp2f(ml[(ww * 16 + q) * 2] - M);
                L += ml[(ww * 16 + q) * 2 + 1] * sc;
                O += fl[ww * 1024 + q * 64 + h] * sc;
            }
            out[(size_t)(b * T_ + q0A + q) * H_ + h] = O / L;
        }
    }

    // ---- pass B: merge tile-B partials ----
    __syncthreads();
    {
        float* ab = (float*)(smem + w * 4096);
#pragma unroll
        for (int ht = 0; ht < 4; ++ht)
#pragma unroll
            for (int r = 0; r < 4; ++r)
                ab[(4 * g + r) * 64 + ht * 16 + lo] = accB[ht][r];
        if (g == 0) {
            ml[(w * 16 + lo) * 2 + 0] = mB;
            ml[(w * 16 + lo) * 2 + 1] = lB;
        }
    }
    __syncthreads();
    {
        const float* fl = (const float*)smem;
#pragma unroll
        for (int jj = 0; jj < 2; ++jj) {
            int e = jj * 512 + tid;
            int q = e >> 6, h = e & 63;
            float M = -1e30f;
#pragma unroll
            for (int ww = 0; ww < 8; ++ww) M = fmaxf(M, ml[(ww * 16 + q) * 2]);
            float L = 0.f, O = 0.f;
#pragma unroll
            for (int ww = 0; ww < 8; ++ww) {
                float sc = exp2f(ml[(ww * 16 + q) * 2] - M);
                L += ml[(ww * 16 + q) * 2 + 1] * sc;
                O += fl[ww * 1024 + q * 64 + h] * sc;
            }
            out[(size_t)(b * T_ + q0B + q) * H_ + h] = O / L;
        }
    }
}

// ---------------------------------------------------------------------------
extern "C" void kernel_launch(void* const* d_in, const int* in_sizes, int n_in,
                              void* d_out, int out_size, void* d_ws, size_t ws_size,
                              hipStream_t stream) {
    const float* x  = (const float*)d_in[0];
    const float* Wk = (const float*)d_in[1];
    const float* bk = (const float*)d_in[2];
    const float* Wq = (const float*)d_in[3];
    const float* bq = (const float*)d_in[4];
    const float* Wv = (const float*)d_in[5];
    const float* bv = (const float*)d_in[6];

    char* ws = (char*)d_ws;
    // ws layout: Wt 384KB | Kg 2MB | Qg 2MB | Vt 2MB
    __bf16* Wt = (__bf16*)(ws);
    __bf16* Kg = (__bf16*)(ws + 393216);
    __bf16* Qg = (__bf16*)(ws + 393216 + 2097152);
    __bf16* Vt = (__bf16*)(ws + 393216 + 2 * 2097152);
    float* out = (float*)d_out;

    prep_wt<<<192, 256, 0, stream>>>(Wk, Wq, Wv, Wt);
    proj_qkv<<<512, 256, 0, stream>>>(x, Wt, bk, bq, bv, Kg, Qg, Vt);
    attn_fwd<<<512, 512, 0, stream>>>(Qg, Kg, Vt, out);
}

// Round 9
// 72.849 us; speedup vs baseline: 1.7222x; 1.7222x over previous
//
#include <hip/hip_runtime.h>

// Head: B=4, T=4096, C=1024, H=64. out = softmax(causal((x@Wq+bq)@(x@Wk+bk)^T * C^-0.5)) @ (x@Wv+bv)
#define B_ 4
#define T_ 4096
#define C_ 1024
#define H_ 64
// C^-0.5 * log2(e): folds softmax scale into Q, moves softmax into exp2 domain.
#define QSCALE 0.045084220027780106f

typedef float  f32x4  __attribute__((ext_vector_type(4)));
typedef __bf16 bf16x8 __attribute__((ext_vector_type(8)));
typedef __bf16 bf16x4 __attribute__((ext_vector_type(4)));

#define MFMA16(a, b, c) __builtin_amdgcn_mfma_f32_16x16x32_bf16((a), (b), (c), 0, 0, 0)

// async global->LDS, 16B per lane; LDS dest is wave-uniform base + lane*16.
__device__ __forceinline__ void gl16(const void* g, void* l) {
    __builtin_amdgcn_global_load_lds(
        (const __attribute__((address_space(1))) void*)g,
        (__attribute__((address_space(3))) void*)l, 16, 0, 0);
}

// ---------------------------------------------------------------------------
// prep: Wt[mat][n][k] = W_mat[k][n] as bf16 (LDS tile transpose). 192 blocks.
// ---------------------------------------------------------------------------
__global__ __launch_bounds__(256) void prep_wt(const float* __restrict__ Wk,
                                               const float* __restrict__ Wq,
                                               const float* __restrict__ Wv,
                                               __bf16* __restrict__ Wt) {
    __shared__ float tile[16][65];
    int tid = threadIdx.x;
    int mat = blockIdx.x >> 6;
    int k0  = (blockIdx.x & 63) * 16;
    const float* W = (mat == 0) ? Wk : ((mat == 1) ? Wq : Wv);
#pragma unroll
    for (int i = 0; i < 4; ++i) {
        int e = i * 256 + tid;
        int ki = e >> 6, n = e & 63;
        tile[ki][n] = W[(size_t)(k0 + ki) * 64 + n];
    }
    __syncthreads();
#pragma unroll
    for (int i = 0; i < 4; ++i) {
        int e = i * 256 + tid;
        int n = e >> 4, kj = e & 15;
        Wt[(size_t)mat * 65536 + (size_t)n * 1024 + k0 + kj] = (__bf16)tile[kj][n];
    }
}

// ---------------------------------------------------------------------------
// proj: m97-style LDS-staged GEMM (R5 version, measured ~18.5us).
// ---------------------------------------------------------------------------
#define STAGE(xd, wd, kk) do {                                              \
    const char* xs_ = xsrc + (size_t)(kk) * 4;                              \
    gl16(xs_,          (xd) + wq * 1024);                                   \
    gl16(xs_ + 65536,  (xd) + 4096 + wq * 1024);                            \
    const char* ws_ = wsrc + (size_t)(kk) * 2;                              \
    gl16(ws_,           (wd) + wq * 1024);                                  \
    gl16(ws_ + 65536,   (wd) + 4096  + wq * 1024);                          \
    gl16(ws_ + 131072,  (wd) + 8192  + wq * 1024);                          \
    gl16(ws_ + 196608,  (wd) + 12288 + wq * 1024);                          \
    gl16(ws_ + 262144,  (wd) + 16384 + wq * 1024);                          \
    gl16(ws_ + 327680,  (wd) + 20480 + wq * 1024);                          \
} while (0)

__global__ __launch_bounds__(256) void proj_qkv(const float* __restrict__ x,
                                                const __bf16* __restrict__ Wt,
                                                const float* __restrict__ bk,
                                                const float* __restrict__ bq,
                                                const float* __restrict__ bv,
                                                __bf16* __restrict__ Kg,
                                                __bf16* __restrict__ Qg,
                                                __bf16* __restrict__ Vt) {
    __shared__ char smem[65536];

    int tid  = threadIdx.x;
    int wq   = tid >> 6;
    int lane = tid & 63;
    int lo = lane & 15, g = lane >> 4;
    int swz = lo & 7;
    int w2 = wq >> 1, wc = wq & 1;
    int r0 = w2 * 16, n0 = wc * 96;
    int row0 = blockIdx.x * 32;

    const char* xsrc = (const char*)(x + (size_t)(row0 + (tid >> 4)) * C_
                                       + (size_t)(((tid & 15) ^ ((tid >> 4) & 7)) * 4));
    const char* wsrc = (const char*)Wt + (size_t)(tid >> 3) * 2048
                                       + (size_t)(((tid & 7) ^ ((tid >> 3) & 7)) * 16);

    char* xcur = smem;          char* xnxt = smem + 8192;
    char* wcur = smem + 16384;  char* wnxt = smem + 40960;

    f32x4 acc[6];
#pragma unroll
    for (int nt = 0; nt < 6; ++nt) acc[nt] = (f32x4){0.f, 0.f, 0.f, 0.f};

    STAGE(xcur, wcur, 0);
    __syncthreads();

#pragma unroll 1
    for (int step = 0; step < 16; ++step) {
        if (step < 15) STAGE(xnxt, wnxt, (step + 1) * 64);

        bf16x8 af[2];
        const char* ap = xcur + (r0 + lo) * 256;
#pragma unroll
        for (int kc = 0; kc < 2; ++kc) {
            int ch0 = kc * 8 + g * 2;
            f32x4 a0 = *(const f32x4*)(ap + ((ch0)     ^ swz) * 16);
            f32x4 a1 = *(const f32x4*)(ap + ((ch0 + 1) ^ swz) * 16);
            bf16x8 t;
            t[0] = (__bf16)a0[0]; t[1] = (__bf16)a0[1];
            t[2] = (__bf16)a0[2]; t[3] = (__bf16)a0[3];
            t[4] = (__bf16)a1[0]; t[5] = (__bf16)a1[1];
            t[6] = (__bf16)a1[2]; t[7] = (__bf16)a1[3];
            af[kc] = t;
        }
#pragma unroll
        for (int nt = 0; nt < 6; ++nt) {
            const char* bp_ = wcur + (n0 + nt * 16 + lo) * 128;
#pragma unroll
            for (int kc = 0; kc < 2; ++kc) {
                bf16x8 bf_ = *(const bf16x8*)(bp_ + ((kc * 4 + g) ^ swz) * 16);
                acc[nt] = MFMA16(af[kc], bf_, acc[nt]);
            }
        }
        __syncthreads();
        char* t1 = xcur; xcur = xnxt; xnxt = t1;
        char* t2 = wcur; wcur = wnxt; wnxt = t2;
    }

    int b_   = row0 >> 12;
    int tloc = row0 & (T_ - 1);
#pragma unroll
    for (int nt = 0; nt < 6; ++nt) {
        int col = n0 + nt * 16 + lo;
        int mat = col >> 6, h = col & 63;
        const float* bp = (mat == 0) ? bk : ((mat == 1) ? bq : bv);
        float bb = bp[h];
        if (mat == 2) {                            // V -> transposed [B][64][T]
            bf16x4 pv;
#pragma unroll
            for (int r = 0; r < 4; ++r) pv[r] = (__bf16)(acc[nt][r] + bb);
            *(bf16x4*)(Vt + (size_t)(b_ * 64 + h) * T_ + tloc + r0 + 4 * g) = pv;
        } else if (mat == 1) {
#pragma unroll
            for (int r = 0; r < 4; ++r)
                Qg[(size_t)(row0 + r0 + 4 * g + r) * H_ + h] = (__bf16)((acc[nt][r] + bb) * QSCALE);
        } else {
#pragma unroll
            for (int r = 0; r < 4; ++r)
                Kg[(size_t)(row0 + r0 + 4 * g + r) * H_ + h] = (__bf16)(acc[nt][r] + bb);
        }
    }
}

// ---------------------------------------------------------------------------
// attn flash iteration reading K/V from swizzled LDS tiles.
// Swapped QK^T: St[k][q] = mfma(K, Q) so softmax rows are lane-local.
// ---------------------------------------------------------------------------
__device__ __forceinline__ void attn_iter_lds(const char* __restrict__ kb_,
                                              const char* __restrict__ vb_,
                                              int k0abs, int q0, bool domask,
                                              bf16x8 qb0, bf16x8 qb1,
                                              f32x4 (&acc)[4], float& m, float& l,
                                              char* pl, int lo, int g) {
    f32x4 st[4];
#pragma unroll
    for (int kt = 0; kt < 4; ++kt) {
        int row = kt * 16 + lo, sw = row & 7;
        bf16x8 ka0 = *(const bf16x8*)(kb_ + row * 128 + ((g ^ sw) << 4));
        bf16x8 ka1 = *(const bf16x8*)(kb_ + row * 128 + (((g + 4) ^ sw) << 4));
        f32x4 z = (f32x4){0.f, 0.f, 0.f, 0.f};
        __builtin_amdgcn_s_setprio(1);
        z = MFMA16(ka0, qb0, z);                   // col=q=lo, row=k=4g+r
        z = MFMA16(ka1, qb1, z);
        __builtin_amdgcn_s_setprio(0);
        st[kt] = z;
    }
    if (domask) {
#pragma unroll
        for (int kt = 0; kt < 4; ++kt)
#pragma unroll
            for (int r = 0; r < 4; ++r) {
                int kabs = k0abs + kt * 16 + 4 * g + r;
                if (kabs > q0 + lo) st[kt][r] = -1e30f;
            }
    }
    float mloc = -1e30f;
#pragma unroll
    for (int kt = 0; kt < 4; ++kt)
#pragma unroll
        for (int r = 0; r < 4; ++r) mloc = fmaxf(mloc, st[kt][r]);
    mloc = fmaxf(mloc, __shfl_xor(mloc, 16));
    mloc = fmaxf(mloc, __shfl_xor(mloc, 32));
    float mnew  = fmaxf(m, mloc);
    float alpha = exp2f(m - mnew);
    float ls = 0.f;
#pragma unroll
    for (int kt = 0; kt < 4; ++kt)
#pragma unroll
        for (int r = 0; r < 4; ++r) {
            float pe = exp2f(st[kt][r] - mnew);
            st[kt][r] = pe;
            ls += pe;
        }
    ls += __shfl_xor(ls, 16);
    ls += __shfl_xor(ls, 32);
    l = l * alpha + ls;
    m = mnew;
#pragma unroll
    for (int r = 0; r < 4; ++r) {
        float ar = __shfl(alpha, 4 * g + r);
#pragma unroll
        for (int ht = 0; ht < 4; ++ht) acc[ht][r] *= ar;
    }
#pragma unroll
    for (int kt = 0; kt < 4; ++kt) {
        bf16x4 pk;
#pragma unroll
        for (int r = 0; r < 4; ++r) pk[r] = (__bf16)st[kt][r];
        int waddr = (lo * 128 + kt * 32 + g * 8) ^ ((lo & 7) << 4);
        *(bf16x4*)(pl + waddr) = pk;
    }
#pragma unroll
    for (int c2 = 0; c2 < 2; ++c2) {
        int raddr = (lo * 128 + c2 * 64 + g * 16) ^ ((lo & 7) << 4);
        bf16x8 pa = *(const bf16x8*)(pl + raddr);
        __builtin_amdgcn_s_setprio(1);
#pragma unroll
        for (int ht = 0; ht < 4; ++ht) {
            int row = ht * 16 + lo, sw = row & 7;
            bf16x8 vb = *(const bf16x8*)(vb_ + row * 128 + (((c2 * 4 + g) ^ sw) << 4));
            acc[ht] = MFMA16(pa, vb, acc[ht]);
        }
        __builtin_amdgcn_s_setprio(0);
    }
}

// ---------------------------------------------------------------------------
// attn: 512 blocks x 256 threads (4 waves). Block = 4 consecutive 16-row
// q-tiles (identical kb-range for all 4 waves) x one kb-parity (2-way split-k
// across blocks). K/V kb-tile (8KB+8KB) staged via global_load_lds
// (pre-swizzled source, linear LDS dest, swizzled reads -> conflict-free),
// double-buffered, one barrier per step; each staged byte feeds 4 waves
// (traffic 532 -> ~130 MB). Rank-folded bid mapping: co-resident blocks
// (bid, bid+256) have step counts summing ~const (stride-256 CU round-robin,
// measured R5/R6), heavy-first. Unnormalized partials + (m,l) -> ws; merge2
// kernel combines parities.
// ---------------------------------------------------------------------------
__global__ __launch_bounds__(256) void attn_fwd(const __bf16* __restrict__ Qg,
                                                const __bf16* __restrict__ Kg,
                                                const __bf16* __restrict__ Vt,
                                                float* __restrict__ partO,
                                                float* __restrict__ partML) {
    // [0,16384) K dbuf, [16384,32768) V dbuf, [32768,40960) P bufs (4 x 2KB)
    __shared__ alignas(16) char smem[40960];

    int tid  = threadIdx.x;
    int w    = tid >> 6;
    int lane = tid & 63;
    int lo = lane & 15, g = lane >> 4;

    // bid -> (rank r, parity p, batch b); fold so (bid, bid+256) ranks sum to 63
    int n = blockIdx.x;
    int u = n & 255, half = n >> 8;
    int r = (half == 0) ? (u >> 3) : (63 - (u >> 3));
    int p = (u >> 2) & 1;
    int b = u & 3;
    int R = 63 - r;                                // kb range of this tile group
    int qt = (r < 32) ? (255 - 4 * r - w) : (4 * R + w);
    int q0 = qt * 16;
    int niter = (R + 2 - p) >> 1;                  // my parity's kb count
    bool maskblk = ((R ^ p) & 1) == 0;             // diagonal kb has my parity

    const char* kgb = (const char*)Kg + (size_t)b * 524288;
    const char* vgb = (const char*)Vt + (size_t)b * 524288;

    // staging offsets (p0 = tid, p1 = tid+256; chunk swizzle c ^ (row&7))
    int sr = tid >> 3;
    int sc = (tid & 7) ^ (sr & 7);
    int koff = sr * 128 + sc * 16;                 // K tile: row stride 128B
    int voff = sr * 8192 + sc * 16;                // V tile: row stride T_*2
    int wb = w * 1024;

    char* pl = smem + 32768 + w * 2048;            // wave-private P buffer

    const __bf16* qp = Qg + (size_t)(b * T_ + q0 + lo) * H_ + g * 8;
    bf16x8 qb0 = *(const bf16x8*)(qp);
    bf16x8 qb1 = *(const bf16x8*)(qp + 32);

    f32x4 acc[4];
#pragma unroll
    for (int ht = 0; ht < 4; ++ht) acc[ht] = (f32x4){0.f, 0.f, 0.f, 0.f};
    float m = -1e30f, l = 0.f;

    if (niter > 0) {
        {   // prologue: stage kb = p into buf 0
            const char* ks = kgb + (size_t)p * 8192;
            const char* vs = vgb + (size_t)p * 128;
            gl16(ks + koff,          smem + wb);
            gl16(ks + koff + 4096,   smem + wb + 4096);
            gl16(vs + voff,          smem + 16384 + wb);
            gl16(vs + voff + 262144, smem + 16384 + wb + 4096);
        }
        __syncthreads();
#pragma unroll 1
        for (int t = 0; t < niter; ++t) {
            int cur = t & 1;
            if (t + 1 < niter) {
                int kb = 2 * (t + 1) + p;
                const char* ks = kgb + (size_t)kb * 8192;
                const char* vs = vgb + (size_t)kb * 128;
                char* kd = smem + (cur ^ 1) * 8192 + wb;
                char* vd = smem + 16384 + (cur ^ 1) * 8192 + wb;
                gl16(ks + koff, kd);
                gl16(ks + koff + 4096, kd + 4096);
                gl16(vs + voff, vd);
                gl16(vs + voff + 262144, vd + 4096);
            }
            int kb = 2 * t + p;
            attn_iter_lds(smem + cur * 8192, smem + 16384 + cur * 8192,
                          kb * 64, q0, (t == niter - 1) && maskblk,
                          qb0, qb1, acc, m, l, pl, lo, g);
            __syncthreads();
        }
    }

    // epilogue: unnormalized partials + (m,l) to ws
    int tg = b * 256 + qt;
    float* po = partO + (size_t)(tg * 2 + p) * 1024;
#pragma unroll
    for (int ht = 0; ht < 4; ++ht)
#pragma unroll
        for (int rr = 0; rr < 4; ++rr)
            po[(4 * g + rr) * 64 + ht * 16 + lo] = acc[ht][rr];
    if (g == 0) {
        partML[(tg * 2 + p) * 32 + lo * 2 + 0] = m;
        partML[(tg * 2 + p) * 32 + lo * 2 + 1] = l;
    }
}

// ---------------------------------------------------------------------------
// merge2: combine the two kb-parity partials per q-row (LSE merge). 1M outputs.
// ---------------------------------------------------------------------------
__global__ __launch_bounds__(256) void merge2(const float* __restrict__ partO,
                                              const float* __restrict__ partML,
                                              float* __restrict__ out) {
    int e = blockIdx.x * 256 + threadIdx.x;        // 0 .. 1048575
    int row = e >> 6, h = e & 63;
    int tg = row >> 4, qr = row & 15;
    float m0 = partML[(tg * 2 + 0) * 32 + qr * 2 + 0];
    float l0 = partML[(tg * 2 + 0) * 32 + qr * 2 + 1];
    float m1 = partML[(tg * 2 + 1) * 32 + qr * 2 + 0];
    float l1 = partML[(tg * 2 + 1) * 32 + qr * 2 + 1];
    float M  = fmaxf(m0, m1);
    float e0 = exp2f(m0 - M), e1 = exp2f(m1 - M);
    float L  = l0 * e0 + l1 * e1;
    float O  = partO[(size_t)(tg * 2 + 0) * 1024 + qr * 64 + h] * e0
             + partO[(size_t)(tg * 2 + 1) * 1024 + qr * 64 + h] * e1;
    out[e] = O / L;
}

// ---------------------------------------------------------------------------
extern "C" void kernel_launch(void* const* d_in, const int* in_sizes, int n_in,
                              void* d_out, int out_size, void* d_ws, size_t ws_size,
                              hipStream_t stream) {
    const float* x  = (const float*)d_in[0];
    const float* Wk = (const float*)d_in[1];
    const float* bk = (const float*)d_in[2];
    const float* Wq = (const float*)d_in[3];
    const float* bq = (const float*)d_in[4];
    const float* Wv = (const float*)d_in[5];
    const float* bv = (const float*)d_in[6];

    char* ws = (char*)d_ws;
    // ws: Wt 384KB | Kg 2MB | Qg 2MB | Vt 2MB | partO 8.4MB | partML 256KB
    __bf16* Wt = (__bf16*)(ws);
    __bf16* Kg = (__bf16*)(ws + 393216);
    __bf16* Qg = (__bf16*)(ws + 393216 + 2097152);
    __bf16* Vt = (__bf16*)(ws + 393216 + 2 * 2097152);
    float* partO  = (float*)(ws + 6684672);
    float* partML = (float*)(ws + 6684672 + 8388608);
    float* out = (float*)d_out;

    prep_wt<<<192, 256, 0, stream>>>(Wk, Wq, Wv, Wt);
    proj_qkv<<<512, 256, 0, stream>>>(x, Wt, bk, bq, bv, Kg, Qg, Vt);
    attn_fwd<<<512, 256, 0, stream>>>(Qg, Kg, Vt, partO, partML);
    merge2<<<4096, 256, 0, stream>>>(partO, partML, out);
}

// Round 10
// 66.627 us; speedup vs baseline: 1.8831x; 1.0934x over previous
//
#include <hip/hip_runtime.h>

// Head: B=4, T=4096, C=1024, H=64. out = softmax(causal((x@Wq+bq)@(x@Wk+bk)^T * C^-0.5)) @ (x@Wv+bv)
#define B_ 4
#define T_ 4096
#define C_ 1024
#define H_ 64
// C^-0.5 * log2(e): folds softmax scale into Q, moves softmax into exp2 domain.
#define QSCALE 0.045084220027780106f

typedef float  f32x4  __attribute__((ext_vector_type(4)));
typedef __bf16 bf16x8 __attribute__((ext_vector_type(8)));
typedef __bf16 bf16x4 __attribute__((ext_vector_type(4)));

#define MFMA16(a, b, c) __builtin_amdgcn_mfma_f32_16x16x32_bf16((a), (b), (c), 0, 0, 0)

// async global->LDS, 16B per lane; LDS dest is wave-uniform base + lane*16.
__device__ __forceinline__ void gl16(const void* g, void* l) {
    __builtin_amdgcn_global_load_lds(
        (const __attribute__((address_space(1))) void*)g,
        (__attribute__((address_space(3))) void*)l, 16, 0, 0);
}

// blocks per batch for the uniform-chunk decomposition (N=6):
// sum_{g=0}^{31} ceil((2g+2)/6) = 187;  grid = 4*187 = 748
#define CPB 187
#define NCHUNK 6

// ---------------------------------------------------------------------------
// prep: Wt[mat][n][k] = W_mat[k][n] as bf16 (LDS tile transpose). 192 blocks.
// ---------------------------------------------------------------------------
__global__ __launch_bounds__(256) void prep_wt(const float* __restrict__ Wk,
                                               const float* __restrict__ Wq,
                                               const float* __restrict__ Wv,
                                               __bf16* __restrict__ Wt) {
    __shared__ float tile[16][65];
    int tid = threadIdx.x;
    int mat = blockIdx.x >> 6;
    int k0  = (blockIdx.x & 63) * 16;
    const float* W = (mat == 0) ? Wk : ((mat == 1) ? Wq : Wv);
#pragma unroll
    for (int i = 0; i < 4; ++i) {
        int e = i * 256 + tid;
        int ki = e >> 6, n = e & 63;
        tile[ki][n] = W[(size_t)(k0 + ki) * 64 + n];
    }
    __syncthreads();
#pragma unroll
    for (int i = 0; i < 4; ++i) {
        int e = i * 256 + tid;
        int n = e >> 4, kj = e & 15;
        Wt[(size_t)mat * 65536 + (size_t)n * 1024 + k0 + kj] = (__bf16)tile[kj][n];
    }
}

// ---------------------------------------------------------------------------
// proj: m97-style LDS-staged GEMM (R5 version, measured ~18.5us).
// ---------------------------------------------------------------------------
#define STAGE(xd, wd, kk) do {                                              \
    const char* xs_ = xsrc + (size_t)(kk) * 4;                              \
    gl16(xs_,          (xd) + wq * 1024);                                   \
    gl16(xs_ + 65536,  (xd) + 4096 + wq * 1024);                            \
    const char* ws_ = wsrc + (size_t)(kk) * 2;                              \
    gl16(ws_,           (wd) + wq * 1024);                                  \
    gl16(ws_ + 65536,   (wd) + 4096  + wq * 1024);                          \
    gl16(ws_ + 131072,  (wd) + 8192  + wq * 1024);                          \
    gl16(ws_ + 196608,  (wd) + 12288 + wq * 1024);                          \
    gl16(ws_ + 262144,  (wd) + 16384 + wq * 1024);                          \
    gl16(ws_ + 327680,  (wd) + 20480 + wq * 1024);                          \
} while (0)

__global__ __launch_bounds__(256) void proj_qkv(const float* __restrict__ x,
                                                const __bf16* __restrict__ Wt,
                                                const float* __restrict__ bk,
                                                const float* __restrict__ bq,
                                                const float* __restrict__ bv,
                                                __bf16* __restrict__ Kg,
                                                __bf16* __restrict__ Qg,
                                                __bf16* __restrict__ Vt) {
    __shared__ char smem[65536];

    int tid  = threadIdx.x;
    int wq   = tid >> 6;
    int lane = tid & 63;
    int lo = lane & 15, g = lane >> 4;
    int swz = lo & 7;
    int w2 = wq >> 1, wc = wq & 1;
    int r0 = w2 * 16, n0 = wc * 96;
    int row0 = blockIdx.x * 32;

    const char* xsrc = (const char*)(x + (size_t)(row0 + (tid >> 4)) * C_
                                       + (size_t)(((tid & 15) ^ ((tid >> 4) & 7)) * 4));
    const char* wsrc = (const char*)Wt + (size_t)(tid >> 3) * 2048
                                       + (size_t)(((tid & 7) ^ ((tid >> 3) & 7)) * 16);

    char* xcur = smem;          char* xnxt = smem + 8192;
    char* wcur = smem + 16384;  char* wnxt = smem + 40960;

    f32x4 acc[6];
#pragma unroll
    for (int nt = 0; nt < 6; ++nt) acc[nt] = (f32x4){0.f, 0.f, 0.f, 0.f};

    STAGE(xcur, wcur, 0);
    __syncthreads();

#pragma unroll 1
    for (int step = 0; step < 16; ++step) {
        if (step < 15) STAGE(xnxt, wnxt, (step + 1) * 64);

        bf16x8 af[2];
        const char* ap = xcur + (r0 + lo) * 256;
#pragma unroll
        for (int kc = 0; kc < 2; ++kc) {
            int ch0 = kc * 8 + g * 2;
            f32x4 a0 = *(const f32x4*)(ap + ((ch0)     ^ swz) * 16);
            f32x4 a1 = *(const f32x4*)(ap + ((ch0 + 1) ^ swz) * 16);
            bf16x8 t;
            t[0] = (__bf16)a0[0]; t[1] = (__bf16)a0[1];
            t[2] = (__bf16)a0[2]; t[3] = (__bf16)a0[3];
            t[4] = (__bf16)a1[0]; t[5] = (__bf16)a1[1];
            t[6] = (__bf16)a1[2]; t[7] = (__bf16)a1[3];
            af[kc] = t;
        }
#pragma unroll
        for (int nt = 0; nt < 6; ++nt) {
            const char* bp_ = wcur + (n0 + nt * 16 + lo) * 128;
#pragma unroll
            for (int kc = 0; kc < 2; ++kc) {
                bf16x8 bf_ = *(const bf16x8*)(bp_ + ((kc * 4 + g) ^ swz) * 16);
                acc[nt] = MFMA16(af[kc], bf_, acc[nt]);
            }
        }
        __syncthreads();
        char* t1 = xcur; xcur = xnxt; xnxt = t1;
        char* t2 = wcur; wcur = wnxt; wnxt = t2;
    }

    int b_   = row0 >> 12;
    int tloc = row0 & (T_ - 1);
#pragma unroll
    for (int nt = 0; nt < 6; ++nt) {
        int col = n0 + nt * 16 + lo;
        int mat = col >> 6, h = col & 63;
        const float* bp = (mat == 0) ? bk : ((mat == 1) ? bq : bv);
        float bb = bp[h];
        if (mat == 2) {                            // V -> transposed [B][64][T]
            bf16x4 pv;
#pragma unroll
            for (int r = 0; r < 4; ++r) pv[r] = (__bf16)(acc[nt][r] + bb);
            *(bf16x4*)(Vt + (size_t)(b_ * 64 + h) * T_ + tloc + r0 + 4 * g) = pv;
        } else if (mat == 1) {
#pragma unroll
            for (int r = 0; r < 4; ++r)
                Qg[(size_t)(row0 + r0 + 4 * g + r) * H_ + h] = (__bf16)((acc[nt][r] + bb) * QSCALE);
        } else {
#pragma unroll
            for (int r = 0; r < 4; ++r)
                Kg[(size_t)(row0 + r0 + 4 * g + r) * H_ + h] = (__bf16)(acc[nt][r] + bb);
        }
    }
}

// ---------------------------------------------------------------------------
// attn flash iteration reading K/V from swizzled LDS tiles.
// Swapped QK^T: St[k][q] = mfma(K, Q) so softmax rows are lane-local.
// ---------------------------------------------------------------------------
__device__ __forceinline__ void attn_iter_lds(const char* __restrict__ kb_,
                                              const char* __restrict__ vb_,
                                              int k0abs, int q0, bool domask,
                                              bf16x8 qb0, bf16x8 qb1,
                                              f32x4 (&acc)[4], float& m, float& l,
                                              char* pl, int lo, int g) {
    f32x4 st[4];
#pragma unroll
    for (int kt = 0; kt < 4; ++kt) {
        int row = kt * 16 + lo, sw = row & 7;
        bf16x8 ka0 = *(const bf16x8*)(kb_ + row * 128 + ((g ^ sw) << 4));
        bf16x8 ka1 = *(const bf16x8*)(kb_ + row * 128 + (((g + 4) ^ sw) << 4));
        f32x4 z = (f32x4){0.f, 0.f, 0.f, 0.f};
        __builtin_amdgcn_s_setprio(1);
        z = MFMA16(ka0, qb0, z);                   // col=q=lo, row=k=4g+r
        z = MFMA16(ka1, qb1, z);
        __builtin_amdgcn_s_setprio(0);
        st[kt] = z;
    }
    if (domask) {
#pragma unroll
        for (int kt = 0; kt < 4; ++kt)
#pragma unroll
            for (int r = 0; r < 4; ++r) {
                int kabs = k0abs + kt * 16 + 4 * g + r;
                if (kabs > q0 + lo) st[kt][r] = -1e30f;
            }
    }
    float mloc = -1e30f;
#pragma unroll
    for (int kt = 0; kt < 4; ++kt)
#pragma unroll
        for (int r = 0; r < 4; ++r) mloc = fmaxf(mloc, st[kt][r]);
    mloc = fmaxf(mloc, __shfl_xor(mloc, 16));
    mloc = fmaxf(mloc, __shfl_xor(mloc, 32));
    float mnew  = fmaxf(m, mloc);
    float alpha = exp2f(m - mnew);
    float ls = 0.f;
#pragma unroll
    for (int kt = 0; kt < 4; ++kt)
#pragma unroll
        for (int r = 0; r < 4; ++r) {
            float pe = exp2f(st[kt][r] - mnew);
            st[kt][r] = pe;
            ls += pe;
        }
    ls += __shfl_xor(ls, 16);
    ls += __shfl_xor(ls, 32);
    l = l * alpha + ls;
    m = mnew;
#pragma unroll
    for (int r = 0; r < 4; ++r) {
        float ar = __shfl(alpha, 4 * g + r);
#pragma unroll
        for (int ht = 0; ht < 4; ++ht) acc[ht][r] *= ar;
    }
#pragma unroll
    for (int kt = 0; kt < 4; ++kt) {
        bf16x4 pk;
#pragma unroll
        for (int r = 0; r < 4; ++r) pk[r] = (__bf16)st[kt][r];
        int waddr = (lo * 128 + kt * 32 + g * 8) ^ ((lo & 7) << 4);
        *(bf16x4*)(pl + waddr) = pk;
    }
#pragma unroll
    for (int c2 = 0; c2 < 2; ++c2) {
        int raddr = (lo * 128 + c2 * 64 + g * 16) ^ ((lo & 7) << 4);
        bf16x8 pa = *(const bf16x8*)(pl + raddr);
        __builtin_amdgcn_s_setprio(1);
#pragma unroll
        for (int ht = 0; ht < 4; ++ht) {
            int row = ht * 16 + lo, sw = row & 7;
            bf16x8 vb = *(const bf16x8*)(vb_ + row * 128 + (((c2 * 4 + g) ^ sw) << 4));
            acc[ht] = MFMA16(pa, vb, acc[ht]);
        }
        __builtin_amdgcn_s_setprio(0);
    }
}

// ---------------------------------------------------------------------------
// attn: 748 blocks x 8 waves. Block = (batch b, q-group g of 128 rows, kb-chunk
// c of <=6 kb tiles). All 8 waves share the staged K/V tile (16KB feeds 128
// q-rows). Uniform ~6-iter blocks -> flat makespan; LDS 48KB -> 3 blocks/CU
// (24 waves/CU). Per-wave causal: wave w's diagonal kb = 2g+(w>>2); skip past
// it, mask at it. Unnormalized bf16 partials + (m,l) -> ws; mergeN combines.
// ---------------------------------------------------------------------------
__global__ __launch_bounds__(512) void attn_fwd(const __bf16* __restrict__ Qg,
                                                const __bf16* __restrict__ Kg,
                                                const __bf16* __restrict__ Vt,
                                                __bf16* __restrict__ partO,
                                                float* __restrict__ partML) {
    // [0,16384) K dbuf, [16384,32768) V dbuf, [32768,49152) P bufs (8 x 2KB)
    __shared__ alignas(16) char smem[49152];

    int tid  = threadIdx.x;
    int w    = tid >> 6;
    int lane = tid & 63;
    int lo = lane & 15, gq = lane >> 4;

    int bid = blockIdx.x;
    int b   = bid / CPB;
    int u   = bid - b * CPB;
    int g = 0, cum = 0;
#pragma unroll 1
    for (; g < 32; ++g) {
        int s = (2 * g + 7) / 6;
        if (u < cum + s) break;
        cum += s;
    }
    int c    = u - cum;
    int j0   = NCHUNK * c;
    int cnt  = min(NCHUNK, 2 * g + 2 - j0);
    int mydiag = 2 * g + (w >> 2);                 // wave's diagonal kb
    int q0   = g * 128 + w * 16;                   // within-batch q base

    const char* kgb = (const char*)Kg + (size_t)b * 524288;
    const char* vgb = (const char*)Vt + (size_t)b * 524288;

    // staging: 512 threads x 16B = one 8KB tile; pre-swizzled source
    int sr = tid >> 3;
    int sc2 = (tid & 7) ^ (sr & 7);
    int koff = sr * 128 + sc2 * 16;                // Kg row stride 128B
    int voff = sr * 8192 + sc2 * 16;               // Vt row stride 8192B
    char* pl = smem + 32768 + w * 2048;

    const __bf16* qp = Qg + (size_t)(b * T_ + q0 + lo) * H_ + gq * 8;
    bf16x8 qb0 = *(const bf16x8*)(qp);
    bf16x8 qb1 = *(const bf16x8*)(qp + 32);

    f32x4 acc[4];
#pragma unroll
    for (int ht = 0; ht < 4; ++ht) acc[ht] = (f32x4){0.f, 0.f, 0.f, 0.f};
    float m = -1e30f, l = 0.f;

    // prologue: stage kb=j0 into buf0
    gl16(kgb + (size_t)j0 * 8192 + koff, smem + w * 1024);
    gl16(vgb + (size_t)j0 * 128 + voff, smem + 16384 + w * 1024);
    __syncthreads();

#pragma unroll 1
    for (int t = 0; t < cnt; ++t) {
        int cur = t & 1;
        if (t + 1 < cnt) {
            int kb = j0 + t + 1;
            gl16(kgb + (size_t)kb * 8192 + koff, smem + (cur ^ 1) * 8192 + w * 1024);
            gl16(vgb + (size_t)kb * 128 + voff, smem + 16384 + (cur ^ 1) * 8192 + w * 1024);
        }
        int kb = j0 + t;
        if (kb <= mydiag) {                        // wave-uniform causal skip
            attn_iter_lds(smem + cur * 8192, smem + 16384 + cur * 8192,
                          kb * 64, q0, kb == mydiag,
                          qb0, qb1, acc, m, l, pl, lo, gq);
        }
        __syncthreads();
    }

    // epilogue: unnormalized bf16 partials + (m,l)
    __bf16* po = partO + (size_t)bid * 8192;       // [128][64]
#pragma unroll
    for (int ht = 0; ht < 4; ++ht)
#pragma unroll
        for (int r = 0; r < 4; ++r)
            po[(w * 16 + 4 * gq + r) * 64 + ht * 16 + lo] = (__bf16)acc[ht][r];
    if (gq == 0) {
        partML[bid * 256 + (w * 16 + lo) * 2 + 0] = m;
        partML[bid * 256 + (w * 16 + lo) * 2 + 1] = l;
    }
}

// ---------------------------------------------------------------------------
// mergeN: LSE-merge the variable-count (<=11) chunk partials per q-row.
// ---------------------------------------------------------------------------
__global__ __launch_bounds__(256) void mergeN(const __bf16* __restrict__ partO,
                                              const float* __restrict__ partML,
                                              float* __restrict__ out) {
    int e = blockIdx.x * 256 + threadIdx.x;        // 0 .. 1048575
    int row = e >> 6, h = e & 63;
    int b = row >> 12, rl = row & 4095;
    int g = rl >> 7, r128 = rl & 127;
    int cum = 0;
#pragma unroll 1
    for (int gg = 0; gg < g; ++gg) cum += (2 * gg + 7) / 6;
    int S = (2 * g + 7) / 6;
    int base = b * CPB + cum;

    float M = -1e30f;
#pragma unroll 1
    for (int c2 = 0; c2 < S; ++c2)
        M = fmaxf(M, partML[(base + c2) * 256 + r128 * 2]);
    float L = 0.f, O = 0.f;
#pragma unroll 1
    for (int c2 = 0; c2 < S; ++c2) {
        float mc = partML[(base + c2) * 256 + r128 * 2];
        float lc = partML[(base + c2) * 256 + r128 * 2 + 1];
        float sc = exp2f(mc - M);
        L += lc * sc;
        O += (float)partO[(size_t)(base + c2) * 8192 + r128 * 64 + h] * sc;
    }
    out[e] = O / L;
}

// ---------------------------------------------------------------------------
extern "C" void kernel_launch(void* const* d_in, const int* in_sizes, int n_in,
                              void* d_out, int out_size, void* d_ws, size_t ws_size,
                              hipStream_t stream) {
    const float* x  = (const float*)d_in[0];
    const float* Wk = (const float*)d_in[1];
    const float* bk = (const float*)d_in[2];
    const float* Wq = (const float*)d_in[3];
    const float* bq = (const float*)d_in[4];
    const float* Wv = (const float*)d_in[5];
    const float* bv = (const float*)d_in[6];

    char* ws = (char*)d_ws;
    // ws: Wt 384K | Kg 2M | Qg 2M | Vt 2M | partO 748*16KB=11.97M | partML 748KB
    __bf16* Wt = (__bf16*)(ws);
    __bf16* Kg = (__bf16*)(ws + 393216);
    __bf16* Qg = (__bf16*)(ws + 393216 + 2097152);
    __bf16* Vt = (__bf16*)(ws + 393216 + 2 * 2097152);
    __bf16* partO  = (__bf16*)(ws + 6684672);
    float*  partML = (float*)(ws + 6684672 + 12255232);
    float* out = (float*)d_out;

    prep_wt<<<192, 256, 0, stream>>>(Wk, Wq, Wv, Wt);
    proj_qkv<<<512, 256, 0, stream>>>(x, Wt, bk, bq, bv, Kg, Qg, Vt);
    attn_fwd<<<4 * CPB, 512, 0, stream>>>(Qg, Kg, Vt, partO, partML);
    mergeN<<<4096, 256, 0, stream>>>(partO, partML, out);
}